// Round 12
// baseline (508.925 us; speedup 1.0000x reference)
//
#include <hip/hip_runtime.h>

// DeepSeek-V2-Lite MoE dims (fixed by the problem)
#define T_TOK 1024
#define H_DIM 2048
#define I_DIM 1408
#define E_NUM 64
#define K_TOP 6
#define CAP   256
#define P_NUM (T_TOK * K_TOP)

typedef __bf16 bf16x8 __attribute__((ext_vector_type(8)));
typedef float  f32x4  __attribute__((ext_vector_type(4)));
typedef unsigned int uint32x2 __attribute__((ext_vector_type(2)));
typedef unsigned int uint32x4 __attribute__((ext_vector_type(4)));

__device__ inline unsigned pack2bf16(float a, float b) {
    unsigned short au = __builtin_bit_cast(unsigned short, (__bf16)a);
    unsigned short bu = __builtin_bit_cast(unsigned short, (__bf16)b);
    return (unsigned)au | ((unsigned)bu << 16);
}

// Non-draining workgroup barrier: waits LDS ops only; global prefetch loads
// stay in flight. No "memory" clobber (would force a vmcnt(0) drain).
__device__ inline void wg_barrier() {
    __builtin_amdgcn_sched_barrier(0);
    asm volatile("s_waitcnt lgkmcnt(0)");
    __builtin_amdgcn_s_barrier();
    __builtin_amdgcn_sched_barrier(0);
}

// ---------------------------------------------------------------- router
// Also zeroes this block's 4 output rows and emits x in bf16.
__global__ __launch_bounds__(256) void router_kernel(
        const float* __restrict__ x, const float* __restrict__ gw,
        float* __restrict__ tw, int* __restrict__ ti, __bf16* __restrict__ xb,
        float* __restrict__ out)
{
    const int t0  = blockIdx.x * 4;
    const int tid = threadIdx.x;
    __shared__ float xs[4][H_DIM];
    __shared__ float part[4][4][E_NUM];

    {
        f32x4 z = (f32x4){0.f, 0.f, 0.f, 0.f};
        f32x4* ob = (f32x4*)(out + (size_t)t0 * H_DIM);
        #pragma unroll
        for (int i = 0; i < 8; ++i) ob[i * 256 + tid] = z;
    }

    #pragma unroll
    for (int tt = 0; tt < 4; ++tt) {
        #pragma unroll
        for (int i = 0; i < 8; ++i) {
            float v = x[(size_t)(t0 + tt) * H_DIM + i * 256 + tid];
            xs[tt][i * 256 + tid] = v;
            xb[(size_t)(t0 + tt) * H_DIM + i * 256 + tid] = (__bf16)v;
        }
    }
    __syncthreads();

    const int e = tid & 63, q = tid >> 6;
    float a0 = 0.f, a1 = 0.f, a2 = 0.f, a3 = 0.f;
    for (int hh = q * 512; hh < q * 512 + 512; ++hh) {
        float g = gw[hh * E_NUM + e];
        a0 += xs[0][hh] * g; a1 += xs[1][hh] * g;
        a2 += xs[2][hh] * g; a3 += xs[3][hh] * g;
    }
    part[q][0][e] = a0; part[q][1][e] = a1; part[q][2][e] = a2; part[q][3][e] = a3;
    __syncthreads();

    const int tt = q;  // wave q handles token q
    float l = part[0][tt][e] + part[1][tt][e] + part[2][tt][e] + part[3][tt][e];
    float m = l;
    #pragma unroll
    for (int s = 32; s; s >>= 1) m = fmaxf(m, __shfl_xor(m, s));
    float p = __expf(l - m);
    float sum = p;
    #pragma unroll
    for (int s = 32; s; s >>= 1) sum += __shfl_xor(sum, s);
    float prob = p / sum;

    float v = prob, wsum = 0.f;
    float tv[K_TOP]; int tix[K_TOP];
    #pragma unroll
    for (int k = 0; k < K_TOP; ++k) {
        float bv = v; int bi = e;
        #pragma unroll
        for (int s = 32; s; s >>= 1) {
            float ov = __shfl_xor(bv, s); int oi = __shfl_xor(bi, s);
            if (ov > bv || (ov == bv && oi < bi)) { bv = ov; bi = oi; }
        }
        tv[k] = bv; tix[k] = bi; wsum += bv;
        if (e == bi) v = -1.0f;
    }
    if (e == 0) {
        #pragma unroll
        for (int k = 0; k < K_TOP; ++k) {
            tw[(t0 + tt) * K_TOP + k] = tv[k] / wsum;
            ti[(t0 + tt) * K_TOP + k] = tix[k];
        }
    }
}

// ---------------------------------------------------------------- dispatch+scan
__global__ __launch_bounds__(1024) void dispatch_scan_kernel(
        const int* __restrict__ ti, int* __restrict__ cnt,
        int* __restrict__ base, int* __restrict__ list)
{
    __shared__ int lcnt[E_NUM];
    const int tid = threadIdx.x;
    if (tid < E_NUM) lcnt[tid] = 0;
    __syncthreads();
    #pragma unroll
    for (int i = 0; i < P_NUM / 1024; ++i) {
        int p = i * 1024 + tid;
        int e = ti[p];
        int slot = atomicAdd(&lcnt[e], 1);
        if (slot < CAP) list[e * CAP + slot] = p;
    }
    __syncthreads();
    if (tid == 0) {
        int acc = 0;
        for (int e = 0; e < E_NUM; ++e) {
            base[e] = acc;
            int c = lcnt[e];
            cnt[e] = c;
            if (c > CAP) c = CAP;
            acc += (c + 15) & ~15;
        }
    }
}

// B LDS column layout: [col][36 dw of k-pairs]; pair index XOR-swizzled:
// p' = p ^ 4*((c4^(c4>>3))&7), c4 = col>>2.
#define B_LDB 36

// ---------------------------------------------------------------- GEMM1
// BN=176 -> 8 n-tiles x 64 experts = 512 active blocks = exactly 2/CU
// (uniform load; removes the 704-block 3-vs-2 CU imbalance tail).
// Waves own 3/3/3/2 column fragments (fg = wv + 4*nf). B staged as 11
// f32x4/thread (flat unit index, k=u/44 hoisted), published as 44
// ds_write_b16 with precomputed swizzled addresses. nt loads, depth-1
// prefetch, non-draining barriers (R9-proven inner structure).
__global__ __launch_bounds__(256, 2) void gemm1_kernel(
        const float* __restrict__ w1, const __bf16* __restrict__ xb,
        const int* __restrict__ cnt, const int* __restrict__ base,
        const int* __restrict__ list, __bf16* __restrict__ hbuf)
{
    const int e  = blockIdx.z;
    const int m0 = blockIdx.y * 128;
    const int nb = blockIdx.x * 176;

    int rows = cnt[e]; if (rows > CAP) rows = CAP;
    const int rows_pad = (rows + 15) & ~15;
    if (m0 >= rows_pad) return;
    int mcount = rows_pad - m0; if (mcount > 128) mcount = 128;
    const int nmf = mcount >> 4;
    const int hb = base[e];

    __shared__ __attribute__((aligned(16))) __bf16 As[128][72];
    __shared__ __attribute__((aligned(16))) unsigned Bs[176 * B_LDB];
    __shared__ int ts[128];

    const int tid = threadIdx.x;
    if (tid < 128) {
        int slot = m0 + tid;
        ts[tid] = (slot < rows) ? (list[e * CAP + slot] / K_TOP) : 0;
    }
    __syncthreads();

    const int lane = tid & 63;
    const int wv   = tid >> 6;
    const int l15  = lane & 15;
    const int lg   = lane >> 4;

    // A staging map (R9 verbatim)
    const int sm = tid >> 3;
    const int sk = (tid & 7) << 3;
    const __bf16* ap[4];
    #pragma unroll
    for (int it = 0; it < 4; ++it)
        ap[it] = xb + (size_t)ts[it * 32 + sm] * H_DIM + sk;

    // B staging: 2816 16B-units = 256 thr x 11. unit u = 256j + tid:
    // k = u/44 (within-tile row), c16 = u%44 (4-col group).
    // Global: 1KB-contiguous per instruction. LDS: 4 b16 writes per unit.
    const float* bbase = w1 + (size_t)e * H_DIM * I_DIM + nb;
    int voff[11];    // element offset of unit u at k0=0
    int laddr[11];   // bf16-element LDS offset of (k, col=4*c16)
    #pragma unroll
    for (int j = 0; j < 11; ++j) {
        int u = 256 * j + tid;
        int kj = u / 44;
        int c16 = u - 44 * kj;
        voff[j] = kj * I_DIM + 4 * c16;
        int Xw = 4 * ((c16 ^ (c16 >> 3)) & 7);
        int pairb = (kj >> 1) ^ Xw;
        laddr[j] = (4 * c16 * B_LDB + pairb) * 2 + (kj & 1);
    }
    __bf16* bsp = (__bf16*)Bs;

    // B fragment read bases: wave wv owns fragments fg = wv + 4*nf (fg < 11).
    f32x4 acc[8][3];
    #pragma unroll
    for (int m = 0; m < 8; ++m)
        #pragma unroll
        for (int nf = 0; nf < 3; ++nf)
            acc[m][nf] = (f32x4){0.f, 0.f, 0.f, 0.f};

    // prologue: loads for step 0
    f32x4 f[11]; bf16x8 av[4];
    #pragma unroll
    for (int j = 0; j < 11; ++j)
        f[j] = __builtin_nontemporal_load((const f32x4*)(bbase + voff[j]));
    #pragma unroll
    for (int it = 0; it < 4; ++it) av[it] = *(const bf16x8*)(ap[it]);

    for (int k0 = 0; k0 < H_DIM; k0 += 64) {
        int kn = k0 + 64; if (kn >= H_DIM) kn = 0;   // wrap: harmless prefetch
        wg_barrier();      // previous step's LDS reads complete (no vmcnt drain)
        // publish tile t
        #pragma unroll
        for (int it = 0; it < 4; ++it)
            *(bf16x8*)(&As[it * 32 + sm][sk]) = av[it];
        #pragma unroll
        for (int j = 0; j < 11; ++j) {
            #pragma unroll
            for (int i = 0; i < 4; ++i)
                bsp[laddr[j] + 2 * B_LDB * i] = (__bf16)f[j][i];
        }
        // reissue loads for t+1 (stay in flight across the barrier)
        {
            const float* bp = bbase + (size_t)kn * I_DIM;
            #pragma unroll
            for (int j = 0; j < 11; ++j)
                f[j] = __builtin_nontemporal_load((const f32x4*)(bp + voff[j]));
            #pragma unroll
            for (int it = 0; it < 4; ++it) av[it] = *(const bf16x8*)(ap[it] + kn);
        }
        wg_barrier();      // tile t visible; prefetch t+1 still outstanding
        // MFMA on tile t
        #pragma unroll
        for (int ks = 0; ks < 2; ++ks) {
            int pbase = ks * 16 + lg * 4;
            #pragma unroll
            for (int nf = 0; nf < 3; ++nf) {
                int fg = wv + 4 * nf;
                if (fg < 11) {
                    int col = 16 * fg + l15;
                    int c4r = col >> 2;
                    int Xr = 4 * ((c4r ^ (c4r >> 3)) & 7);
                    bf16x8 b = *(const bf16x8*)(&Bs[col * B_LDB + (pbase ^ Xr)]);
                    #pragma unroll
                    for (int m = 0; m < 8; ++m) {
                        if (m < nmf) {
                            bf16x8 a = *(const bf16x8*)(&As[m * 16 + l15][ks * 32 + lg * 8]);
                            acc[m][nf] = __builtin_amdgcn_mfma_f32_16x16x32_bf16(a, b, acc[m][nf], 0, 0, 0);
                        }
                    }
                }
            }
        }
    }

    #pragma unroll
    for (int m = 0; m < 8; ++m) {
        if (m < nmf) {
            #pragma unroll
            for (int nf = 0; nf < 3; ++nf) {
                int fg = wv + 4 * nf;
                if (fg < 11) {
                    #pragma unroll
                    for (int j = 0; j < 4; ++j) {
                        int row = m * 16 + lg * 4 + j;
                        int col = nb + 16 * fg + l15;
                        float v = acc[m][nf][j];
                        float s = v / (1.0f + __expf(-v));
                        hbuf[(size_t)(hb + m0 + row) * I_DIM + col] = (__bf16)s;
                    }
                }
            }
        }
    }
}

// ---------------------------------------------------------------- GEMM2
// (R11 verbatim) BN=256, BK=64, (256,2): 512 active blocks = 2/CU, one clean
// round. 1KB-contiguous nt weight loads, depth-1 prefetch, non-draining
// barriers, atomic fp32 epilogue.
__global__ __launch_bounds__(256, 2) void gemm2_kernel(
        const float* __restrict__ w2, const __bf16* __restrict__ hbuf,
        const int* __restrict__ cnt, const int* __restrict__ base,
        const int* __restrict__ list, const float* __restrict__ tw,
        float* __restrict__ out)
{
    const int e  = blockIdx.z;
    const int m0 = blockIdx.y * 128;
    const int nb = blockIdx.x * 256;

    int rows = cnt[e]; if (rows > CAP) rows = CAP;
    const int rows_pad = (rows + 15) & ~15;
    if (m0 >= rows_pad) return;
    int mcount = rows_pad - m0; if (mcount > 128) mcount = 128;
    const int nmf = mcount >> 4;
    const int hb = base[e];

    __shared__ __attribute__((aligned(16))) __bf16 As[128][72];
    __shared__ __attribute__((aligned(16))) unsigned Bs[256 * B_LDB];
    __shared__ int ps[128];
    __shared__ float tws[128];

    const int tid = threadIdx.x;
    if (tid < 128) {
        int slot = m0 + tid;
        int p = (slot < rows) ? list[e * CAP + slot] : -1;
        ps[tid] = p;
        tws[tid] = (p >= 0) ? tw[p] : 0.f;
    }
    __syncthreads();

    const int lane = tid & 63;
    const int wv   = tid >> 6;
    const int l15  = lane & 15;
    const int lg   = lane >> 4;
    const int wm   = wv >> 1;
    const int wn   = wv & 1;

    const int sm = tid >> 3;
    const int sk = (tid & 7) << 3;
    const __bf16* abase = hbuf + (size_t)(hb + m0 + sm) * I_DIM + sk;

    const int c4 = tid & 63;
    const int kq = tid >> 6;
    const int Xw = 4 * ((c4 ^ (c4 >> 3)) & 7);
    const float* bload = w2 + (size_t)e * I_DIM * H_DIM
                            + (size_t)(16 * kq) * H_DIM + (nb + 4 * c4);

    f32x4 acc[4][8];
    #pragma unroll
    for (int m = 0; m < 4; ++m)
        #pragma unroll
        for (int nf = 0; nf < 8; ++nf)
            acc[m][nf] = (f32x4){0.f, 0.f, 0.f, 0.f};

    f32x4 f[16]; bf16x8 av[4];
    #pragma unroll
    for (int r = 0; r < 16; ++r)
        f[r] = __builtin_nontemporal_load((const f32x4*)(bload + (size_t)r * H_DIM));
    #pragma unroll
    for (int it = 0; it < 4; ++it)
        av[it] = *(const bf16x8*)(abase + (size_t)(it * 32) * I_DIM);

    for (int k0 = 0; k0 < I_DIM; k0 += 64) {
        int kn = k0 + 64; if (kn >= I_DIM) kn = 0;
        wg_barrier();
        #pragma unroll
        for (int it = 0; it < 4; ++it)
            *(bf16x8*)(&As[it * 32 + sm][sk]) = av[it];
        #pragma unroll
        for (int i = 0; i < 4; ++i) {
            int c = 4 * c4 + i;
            uint32x4 q0, q1;
            #pragma unroll
            for (int r = 0; r < 4; ++r)
                q0[r] = pack2bf16(f[2 * r][i], f[2 * r + 1][i]);
            #pragma unroll
            for (int r = 0; r < 4; ++r)
                q1[r] = pack2bf16(f[8 + 2 * r][i], f[9 + 2 * r][i]);
            *(uint32x4*)(&Bs[c * B_LDB + ((8 * kq) ^ Xw)])     = q0;
            *(uint32x4*)(&Bs[c * B_LDB + ((8 * kq + 4) ^ Xw)]) = q1;
        }
        {
            const float* bp = bload + (size_t)kn * H_DIM;
            #pragma unroll
            for (int r = 0; r < 16; ++r)
                f[r] = __builtin_nontemporal_load((const f32x4*)(bp + (size_t)r * H_DIM));
            #pragma unroll
            for (int it = 0; it < 4; ++it)
                av[it] = *(const bf16x8*)(abase + (size_t)(it * 32) * I_DIM + kn);
        }
        wg_barrier();
        #pragma unroll
        for (int ks = 0; ks < 2; ++ks) {
            int pbase = ks * 16 + lg * 4;
            bf16x8 a[4];
            #pragma unroll
            for (int m = 0; m < 4; ++m)
                a[m] = *(const bf16x8*)(&As[wm * 64 + m * 16 + l15][ks * 32 + lg * 8]);
            #pragma unroll
            for (int nf = 0; nf < 8; ++nf) {
                int col = wn * 128 + nf * 16 + l15;
                int c4r = col >> 2;
                int Xr = 4 * ((c4r ^ (c4r >> 3)) & 7);
                bf16x8 b = *(const bf16x8*)(&Bs[col * B_LDB + (pbase ^ Xr)]);
                #pragma unroll
                for (int m = 0; m < 4; ++m) {
                    if (wm * 4 + m < nmf)
                        acc[m][nf] = __builtin_amdgcn_mfma_f32_16x16x32_bf16(a[m], b, acc[m][nf], 0, 0, 0);
                }
            }
        }
    }

    #pragma unroll
    for (int m = 0; m < 4; ++m) {
        if (wm * 4 + m < nmf) {
            #pragma unroll
            for (int nf = 0; nf < 8; ++nf) {
                #pragma unroll
                for (int j = 0; j < 4; ++j) {
                    int row = wm * 64 + m * 16 + lg * 4 + j;
                    int p = ps[row];
                    if (p >= 0) {
                        int t = p / K_TOP;
                        float v = acc[m][nf][j] * tws[row];
                        atomicAdd(&out[(size_t)t * H_DIM + (nb + wn * 128 + nf * 16 + l15)], v);
                    }
                }
            }
        }
    }
}

// ---------------------------------------------------------------- launch
extern "C" void kernel_launch(void* const* d_in, const int* in_sizes, int n_in,
                              void* d_out, int out_size, void* d_ws, size_t ws_size,
                              hipStream_t stream) {
    const float* x  = (const float*)d_in[0];
    const float* gw = (const float*)d_in[1];
    const float* w1 = (const float*)d_in[2];
    const float* w2 = (const float*)d_in[3];
    float* out = (float*)d_out;

    char* ws = (char*)d_ws;
    int*    cnt  = (int*)ws;
    int*    base = (int*)(ws + 256);
    int*    list = (int*)(ws + 512);
    float*  tw   = (float*)(ws + 66048);
    int*    ti   = (int*)(ws + 90624);
    __bf16* xb   = (__bf16*)(ws + 131072);
    __bf16* hbuf = (__bf16*)(ws + 4325376);

    hipLaunchKernelGGL(router_kernel, dim3(T_TOK / 4), dim3(256), 0, stream,
                       x, gw, tw, ti, xb, out);
    hipLaunchKernelGGL(dispatch_scan_kernel, dim3(1), dim3(1024), 0, stream,
                       ti, cnt, base, list);
    hipLaunchKernelGGL(gemm1_kernel, dim3(I_DIM / 176, 2, E_NUM), dim3(256), 0, stream,
                       w1, xb, cnt, base, list, hbuf);
    hipLaunchKernelGGL(gemm2_kernel, dim3(H_DIM / 256, 2, E_NUM), dim3(256), 0, stream,
                       w2, hbuf, cnt, base, list, tw, out);
}

// Round 13
// 411.919 us; speedup vs baseline: 1.2355x; 1.2355x over previous
//
#include <hip/hip_runtime.h>

// DeepSeek-V2-Lite MoE dims (fixed by the problem)
#define T_TOK 1024
#define H_DIM 2048
#define I_DIM 1408
#define E_NUM 64
#define K_TOP 6
#define CAP   256
#define P_NUM (T_TOK * K_TOP)

typedef __bf16 bf16x8 __attribute__((ext_vector_type(8)));
typedef float  f32x4  __attribute__((ext_vector_type(4)));
typedef unsigned int uint32x2 __attribute__((ext_vector_type(2)));
typedef unsigned int uint32x4 __attribute__((ext_vector_type(4)));

__device__ inline unsigned pack2bf16(float a, float b) {
    unsigned short au = __builtin_bit_cast(unsigned short, (__bf16)a);
    unsigned short bu = __builtin_bit_cast(unsigned short, (__bf16)b);
    return (unsigned)au | ((unsigned)bu << 16);
}

// Non-draining workgroup barrier: waits LDS ops only; global prefetch loads
// stay in flight. No "memory" clobber (would force a vmcnt(0) drain).
__device__ inline void wg_barrier() {
    __builtin_amdgcn_sched_barrier(0);
    asm volatile("s_waitcnt lgkmcnt(0)");
    __builtin_amdgcn_s_barrier();
    __builtin_amdgcn_sched_barrier(0);
}

// ---------------------------------------------------------------- router
// Also zeroes this block's 4 output rows (replaces a zero_out kernel) and
// emits x in bf16.
__global__ __launch_bounds__(256) void router_kernel(
        const float* __restrict__ x, const float* __restrict__ gw,
        float* __restrict__ tw, int* __restrict__ ti, __bf16* __restrict__ xb,
        float* __restrict__ out)
{
    const int t0  = blockIdx.x * 4;
    const int tid = threadIdx.x;
    __shared__ float xs[4][H_DIM];
    __shared__ float part[4][4][E_NUM];

    // zero out rows t0..t0+3 (4 x 2048 floats = 2048 f32x4)
    {
        f32x4 z = (f32x4){0.f, 0.f, 0.f, 0.f};
        f32x4* ob = (f32x4*)(out + (size_t)t0 * H_DIM);
        #pragma unroll
        for (int i = 0; i < 8; ++i) ob[i * 256 + tid] = z;
    }

    #pragma unroll
    for (int tt = 0; tt < 4; ++tt) {
        #pragma unroll
        for (int i = 0; i < 8; ++i) {
            float v = x[(size_t)(t0 + tt) * H_DIM + i * 256 + tid];
            xs[tt][i * 256 + tid] = v;
            xb[(size_t)(t0 + tt) * H_DIM + i * 256 + tid] = (__bf16)v;
        }
    }
    __syncthreads();

    const int e = tid & 63, q = tid >> 6;
    float a0 = 0.f, a1 = 0.f, a2 = 0.f, a3 = 0.f;
    for (int hh = q * 512; hh < q * 512 + 512; ++hh) {
        float g = gw[hh * E_NUM + e];
        a0 += xs[0][hh] * g; a1 += xs[1][hh] * g;
        a2 += xs[2][hh] * g; a3 += xs[3][hh] * g;
    }
    part[q][0][e] = a0; part[q][1][e] = a1; part[q][2][e] = a2; part[q][3][e] = a3;
    __syncthreads();

    const int tt = q;  // wave q handles token q
    float l = part[0][tt][e] + part[1][tt][e] + part[2][tt][e] + part[3][tt][e];
    float m = l;
    #pragma unroll
    for (int s = 32; s; s >>= 1) m = fmaxf(m, __shfl_xor(m, s));
    float p = __expf(l - m);
    float sum = p;
    #pragma unroll
    for (int s = 32; s; s >>= 1) sum += __shfl_xor(sum, s);
    float prob = p / sum;

    float v = prob, wsum = 0.f;
    float tv[K_TOP]; int tix[K_TOP];
    #pragma unroll
    for (int k = 0; k < K_TOP; ++k) {
        float bv = v; int bi = e;
        #pragma unroll
        for (int s = 32; s; s >>= 1) {
            float ov = __shfl_xor(bv, s); int oi = __shfl_xor(bi, s);
            if (ov > bv || (ov == bv && oi < bi)) { bv = ov; bi = oi; }
        }
        tv[k] = bv; tix[k] = bi; wsum += bv;
        if (e == bi) v = -1.0f;
    }
    if (e == 0) {
        #pragma unroll
        for (int k = 0; k < K_TOP; ++k) {
            tw[(t0 + tt) * K_TOP + k] = tv[k] / wsum;
            ti[(t0 + tt) * K_TOP + k] = tix[k];
        }
    }
}

// ---------------------------------------------------------------- dispatch+scan
__global__ __launch_bounds__(1024) void dispatch_scan_kernel(
        const int* __restrict__ ti, int* __restrict__ cnt,
        int* __restrict__ base, int* __restrict__ list)
{
    __shared__ int lcnt[E_NUM];
    const int tid = threadIdx.x;
    if (tid < E_NUM) lcnt[tid] = 0;
    __syncthreads();
    #pragma unroll
    for (int i = 0; i < P_NUM / 1024; ++i) {
        int p = i * 1024 + tid;
        int e = ti[p];
        int slot = atomicAdd(&lcnt[e], 1);
        if (slot < CAP) list[e * CAP + slot] = p;
    }
    __syncthreads();
    if (tid == 0) {
        int acc = 0;
        for (int e = 0; e < E_NUM; ++e) {
            base[e] = acc;
            int c = lcnt[e];
            cnt[e] = c;
            if (c > CAP) c = CAP;
            acc += (c + 15) & ~15;
        }
    }
}

// B LDS column layout: pair index XOR-swizzled: p' = p ^ 4*((c4^(c4>>3))&7).
#define B_LDB 36

// ---------------------------------------------------------------- GEMM1
// Best-known gemm1 (R9/R11): nt B loads, depth-1 prefetch, non-draining
// barriers, BN=128, (256,3).
__global__ __launch_bounds__(256, 3) void gemm1_kernel(
        const float* __restrict__ w1, const __bf16* __restrict__ xb,
        const int* __restrict__ cnt, const int* __restrict__ base,
        const int* __restrict__ list, __bf16* __restrict__ hbuf)
{
    const int e  = blockIdx.z;
    const int m0 = blockIdx.y * 128;
    const int nb = blockIdx.x * 128;

    int rows = cnt[e]; if (rows > CAP) rows = CAP;
    const int rows_pad = (rows + 15) & ~15;
    if (m0 >= rows_pad) return;
    int mcount = rows_pad - m0; if (mcount > 128) mcount = 128;
    const int nmf = mcount >> 4;
    const int hb = base[e];

    __shared__ __attribute__((aligned(16))) __bf16 As[128][72];
    __shared__ __attribute__((aligned(16))) unsigned Bs[128 * B_LDB];
    __shared__ int ts[128];

    const int tid = threadIdx.x;
    if (tid < 128) {
        int slot = m0 + tid;
        ts[tid] = (slot < rows) ? (list[e * CAP + slot] / K_TOP) : 0;
    }
    __syncthreads();

    const int lane = tid & 63;
    const int wv   = tid >> 6;
    const int l15  = lane & 15;
    const int lg   = lane >> 4;

    const int sm = tid >> 3;
    const int sk = (tid & 7) << 3;
    const __bf16* ap[4];
    #pragma unroll
    for (int it = 0; it < 4; ++it)
        ap[it] = xb + (size_t)ts[it * 32 + sm] * H_DIM + sk;

    const int c4 = tid & 31;
    const int kb = tid >> 5;
    const int Xw = 4 * ((c4 ^ (c4 >> 3)) & 7);
    const float* bload = w1 + (size_t)e * H_DIM * I_DIM + (nb + 4 * c4);

    int cB0 = wv * 32 + l15;
    int cB1 = cB0 + 16;
    int c4r0 = cB0 >> 2, c4r1 = cB1 >> 2;
    const int Xr0 = 4 * ((c4r0 ^ (c4r0 >> 3)) & 7);
    const int Xr1 = 4 * ((c4r1 ^ (c4r1 >> 3)) & 7);
    const unsigned* bfp0 = Bs + cB0 * B_LDB;
    const unsigned* bfp1 = Bs + cB1 * B_LDB;

    f32x4 acc[8][2];
    #pragma unroll
    for (int m = 0; m < 8; ++m) {
        acc[m][0] = (f32x4){0.f, 0.f, 0.f, 0.f};
        acc[m][1] = (f32x4){0.f, 0.f, 0.f, 0.f};
    }

    f32x4 f[8]; bf16x8 av[4];
    {
        const float* bp = bload;
        #pragma unroll
        for (int r = 0; r < 4; ++r)
            f[r] = __builtin_nontemporal_load((const f32x4*)(bp + (size_t)(4 * kb + r) * I_DIM));
        #pragma unroll
        for (int r = 0; r < 4; ++r)
            f[4 + r] = __builtin_nontemporal_load((const f32x4*)(bp + (size_t)(4 * kb + 32 + r) * I_DIM));
        #pragma unroll
        for (int it = 0; it < 4; ++it) av[it] = *(const bf16x8*)(ap[it]);
    }

    for (int k0 = 0; k0 < H_DIM; k0 += 64) {
        int kn = k0 + 64; if (kn >= H_DIM) kn = 0;
        wg_barrier();
        #pragma unroll
        for (int it = 0; it < 4; ++it)
            *(bf16x8*)(&As[it * 32 + sm][sk]) = av[it];
        #pragma unroll
        for (int b = 0; b < 2; ++b) {
            #pragma unroll
            for (int i = 0; i < 4; ++i) {
                unsigned lo = pack2bf16(f[4 * b + 0][i], f[4 * b + 1][i]);
                unsigned hi = pack2bf16(f[4 * b + 2][i], f[4 * b + 3][i]);
                int c = 4 * c4 + i;
                int p = 2 * kb + 16 * b;
                *(uint32x2*)(&Bs[c * B_LDB + (p ^ Xw)]) = (uint32x2){lo, hi};
            }
        }
        {
            const float* bp = bload + (size_t)(kn + 4 * kb) * I_DIM;
            #pragma unroll
            for (int r = 0; r < 4; ++r)
                f[r] = __builtin_nontemporal_load((const f32x4*)(bp + (size_t)r * I_DIM));
            const float* bp2 = bp + (size_t)32 * I_DIM;
            #pragma unroll
            for (int r = 0; r < 4; ++r)
                f[4 + r] = __builtin_nontemporal_load((const f32x4*)(bp2 + (size_t)r * I_DIM));
            #pragma unroll
            for (int it = 0; it < 4; ++it) av[it] = *(const bf16x8*)(ap[it] + kn);
        }
        wg_barrier();
        #pragma unroll
        for (int ks = 0; ks < 2; ++ks) {
            int pbase = ks * 16 + lg * 4;
            bf16x8 b0 = *(const bf16x8*)(bfp0 + (pbase ^ Xr0));
            bf16x8 b1 = *(const bf16x8*)(bfp1 + (pbase ^ Xr1));
            #pragma unroll
            for (int m = 0; m < 8; ++m) {
                if (m < nmf) {
                    bf16x8 a = *(const bf16x8*)(&As[m * 16 + l15][ks * 32 + lg * 8]);
                    acc[m][0] = __builtin_amdgcn_mfma_f32_16x16x32_bf16(a, b0, acc[m][0], 0, 0, 0);
                    acc[m][1] = __builtin_amdgcn_mfma_f32_16x16x32_bf16(a, b1, acc[m][1], 0, 0, 0);
                }
            }
        }
    }

    const int nw = nb + wv * 32;
    #pragma unroll
    for (int m = 0; m < 8; ++m) {
        if (m < nmf) {
            #pragma unroll
            for (int nf = 0; nf < 2; ++nf) {
                #pragma unroll
                for (int j = 0; j < 4; ++j) {
                    int row = m * 16 + lg * 4 + j;
                    int col = nw + nf * 16 + l15;
                    float v = acc[m][nf][j];
                    float s = v / (1.0f + __expf(-v));
                    hbuf[(size_t)(hb + m0 + row) * I_DIM + col] = (__bf16)s;
                }
            }
        }
    }
}

// ---------------------------------------------------------------- GEMM2
// BN=256, BK=64, (256,2): 512 active blocks = 2/CU, one clean round.
// 1KB-contiguous nt weight loads, depth-1 prefetch, non-draining barriers,
// atomic fp32 epilogue.
__global__ __launch_bounds__(256, 2) void gemm2_kernel(
        const float* __restrict__ w2, const __bf16* __restrict__ hbuf,
        const int* __restrict__ cnt, const int* __restrict__ base,
        const int* __restrict__ list, const float* __restrict__ tw,
        float* __restrict__ out)
{
    const int e  = blockIdx.z;
    const int m0 = blockIdx.y * 128;
    const int nb = blockIdx.x * 256;

    int rows = cnt[e]; if (rows > CAP) rows = CAP;
    const int rows_pad = (rows + 15) & ~15;
    if (m0 >= rows_pad) return;
    int mcount = rows_pad - m0; if (mcount > 128) mcount = 128;
    const int nmf = mcount >> 4;
    const int hb = base[e];

    __shared__ __attribute__((aligned(16))) __bf16 As[128][72];
    __shared__ __attribute__((aligned(16))) unsigned Bs[256 * B_LDB];
    __shared__ int ps[128];
    __shared__ float tws[128];

    const int tid = threadIdx.x;
    if (tid < 128) {
        int slot = m0 + tid;
        int p = (slot < rows) ? list[e * CAP + slot] : -1;
        ps[tid] = p;
        tws[tid] = (p >= 0) ? tw[p] : 0.f;
    }
    __syncthreads();

    const int lane = tid & 63;
    const int wv   = tid >> 6;
    const int l15  = lane & 15;
    const int lg   = lane >> 4;
    const int wm   = wv >> 1;
    const int wn   = wv & 1;

    const int sm = tid >> 3;
    const int sk = (tid & 7) << 3;
    const __bf16* abase = hbuf + (size_t)(hb + m0 + sm) * I_DIM + sk;

    // B staging: c4 = tid&63 -> cols 4c4..4c4+3; kq = tid>>6 -> rows 16kq..+15.
    // Each load instr: 64 lanes x 16B = 1KB contiguous.
    const int c4 = tid & 63;
    const int kq = tid >> 6;
    const int Xw = 4 * ((c4 ^ (c4 >> 3)) & 7);
    const float* bload = w2 + (size_t)e * I_DIM * H_DIM
                            + (size_t)(16 * kq) * H_DIM + (nb + 4 * c4);

    f32x4 acc[4][8];
    #pragma unroll
    for (int m = 0; m < 4; ++m)
        #pragma unroll
        for (int nf = 0; nf < 8; ++nf)
            acc[m][nf] = (f32x4){0.f, 0.f, 0.f, 0.f};

    f32x4 f[16]; bf16x8 av[4];
    #pragma unroll
    for (int r = 0; r < 16; ++r)
        f[r] = __builtin_nontemporal_load((const f32x4*)(bload + (size_t)r * H_DIM));
    #pragma unroll
    for (int it = 0; it < 4; ++it)
        av[it] = *(const bf16x8*)(abase + (size_t)(it * 32) * I_DIM);

    for (int k0 = 0; k0 < I_DIM; k0 += 64) {
        int kn = k0 + 64; if (kn >= I_DIM) kn = 0;
        wg_barrier();
        #pragma unroll
        for (int it = 0; it < 4; ++it)
            *(bf16x8*)(&As[it * 32 + sm][sk]) = av[it];
        #pragma unroll
        for (int i = 0; i < 4; ++i) {
            int c = 4 * c4 + i;
            uint32x4 q0, q1;
            #pragma unroll
            for (int r = 0; r < 4; ++r)
                q0[r] = pack2bf16(f[2 * r][i], f[2 * r + 1][i]);
            #pragma unroll
            for (int r = 0; r < 4; ++r)
                q1[r] = pack2bf16(f[8 + 2 * r][i], f[9 + 2 * r][i]);
            *(uint32x4*)(&Bs[c * B_LDB + ((8 * kq) ^ Xw)])     = q0;
            *(uint32x4*)(&Bs[c * B_LDB + ((8 * kq + 4) ^ Xw)]) = q1;
        }
        {
            const float* bp = bload + (size_t)kn * H_DIM;
            #pragma unroll
            for (int r = 0; r < 16; ++r)
                f[r] = __builtin_nontemporal_load((const f32x4*)(bp + (size_t)r * H_DIM));
            #pragma unroll
            for (int it = 0; it < 4; ++it)
                av[it] = *(const bf16x8*)(abase + (size_t)(it * 32) * I_DIM + kn);
        }
        wg_barrier();
        #pragma unroll
        for (int ks = 0; ks < 2; ++ks) {
            int pbase = ks * 16 + lg * 4;
            bf16x8 a[4];
            #pragma unroll
            for (int m = 0; m < 4; ++m)
                a[m] = *(const bf16x8*)(&As[wm * 64 + m * 16 + l15][ks * 32 + lg * 8]);
            #pragma unroll
            for (int nf = 0; nf < 8; ++nf) {
                int col = wn * 128 + nf * 16 + l15;
                int c4r = col >> 2;
                int Xr = 4 * ((c4r ^ (c4r >> 3)) & 7);
                bf16x8 b = *(const bf16x8*)(&Bs[col * B_LDB + (pbase ^ Xr)]);
                #pragma unroll
                for (int m = 0; m < 4; ++m) {
                    if (wm * 4 + m < nmf)
                        acc[m][nf] = __builtin_amdgcn_mfma_f32_16x16x32_bf16(a[m], b, acc[m][nf], 0, 0, 0);
                }
            }
        }
    }

    #pragma unroll
    for (int m = 0; m < 4; ++m) {
        if (wm * 4 + m < nmf) {
            #pragma unroll
            for (int nf = 0; nf < 8; ++nf) {
                #pragma unroll
                for (int j = 0; j < 4; ++j) {
                    int row = wm * 64 + m * 16 + lg * 4 + j;
                    int p = ps[row];
                    if (p >= 0) {
                        int t = p / K_TOP;
                        float v = acc[m][nf][j] * tws[row];
                        atomicAdd(&out[(size_t)t * H_DIM + (nb + wn * 128 + nf * 16 + l15)], v);
                    }
                }
            }
        }
    }
}

// ---------------------------------------------------------------- launch
extern "C" void kernel_launch(void* const* d_in, const int* in_sizes, int n_in,
                              void* d_out, int out_size, void* d_ws, size_t ws_size,
                              hipStream_t stream) {
    const float* x  = (const float*)d_in[0];
    const float* gw = (const float*)d_in[1];
    const float* w1 = (const float*)d_in[2];
    const float* w2 = (const float*)d_in[3];
    float* out = (float*)d_out;

    char* ws = (char*)d_ws;
    int*    cnt  = (int*)ws;
    int*    base = (int*)(ws + 256);
    int*    list = (int*)(ws + 512);
    float*  tw   = (float*)(ws + 66048);
    int*    ti   = (int*)(ws + 90624);
    __bf16* xb   = (__bf16*)(ws + 131072);
    __bf16* hbuf = (__bf16*)(ws + 4325376);

    hipLaunchKernelGGL(router_kernel, dim3(T_TOK / 4), dim3(256), 0, stream,
                       x, gw, tw, ti, xb, out);
    hipLaunchKernelGGL(dispatch_scan_kernel, dim3(1), dim3(1024), 0, stream,
                       ti, cnt, base, list);
    hipLaunchKernelGGL(gemm1_kernel, dim3(I_DIM / 128, 2, E_NUM), dim3(256), 0, stream,
                       w1, xb, cnt, base, list, hbuf);
    hipLaunchKernelGGL(gemm2_kernel, dim3(H_DIM / 256, 2, E_NUM), dim3(256), 0, stream,
                       w2, hbuf, cnt, base, list, tw, out);
}